// Round 13
// baseline (619.150 us; speedup 1.0000x reference)
//
#include <hip/hip_runtime.h>

typedef long long i64;
typedef unsigned short u16;
typedef __attribute__((ext_vector_type(8))) short short8;
typedef __attribute__((ext_vector_type(4))) float f32x4;

#define Bv 8
#define Nv 1024
#define Dv 768
#define Hh 4
#define DKv 192
#define BND ((i64)Bv * Nv * Dv)      /* 6,291,456  */
#define HBND ((i64)Hh * BND)         /* 25,165,824 */

__device__ __forceinline__ u16 f2bf(float f) {
    unsigned u = __builtin_bit_cast(unsigned, f);
    u += 0x7fffu + ((u >> 16) & 1u);
    return (u16)(u >> 16);
}
__device__ __forceinline__ float bf2f(u16 h) {
    unsigned u = ((unsigned)h) << 16;
    return __builtin_bit_cast(float, u);
}

// async global->LDS, 16B per lane. LDS dest must be wave-uniform base.
__device__ __forceinline__ void gl_lds16(const u16* g, u16* l) {
    __builtin_amdgcn_global_load_lds(
        (const __attribute__((address_space(1))) void*)g,
        (__attribute__((address_space(3))) void*)l, 16, 0, 0);
}

// ---------------------------------------------------------------------------
// bf16 MFMA GEMM (m97-structure): 128x128 tile, BK=64, 256 threads, ~790 TF.
// (unchanged from round 7 — see comments there)
// ---------------------------------------------------------------------------
template <int EPI, bool CATK, int ORD, int NBN, int NBM, int NZ>
__global__ __launch_bounds__(256) void gemm_bf16(
    const u16* __restrict__ A, i64 sA, int lda,
    const u16* __restrict__ Bt, i64 sBt, int ldbt, int zmaskBt,
    const float* __restrict__ bias, i64 sBias, const float* __restrict__ bias2,
    void* __restrict__ Cv, i64 sC, int ldc, int K, int koff)
{
    __shared__ u16 Asb[128 * 64];
    __shared__ u16 Bsb[128 * 64];

    const int L = (blockIdx.x & 7) * ((NBN * NBM * NZ) >> 3) + (blockIdx.x >> 3);
    int bn, bm, z;
    if (ORD == 0) {
        bn = L % NBN; const int t2 = L / NBN; bm = t2 % NBM; z = t2 / NBM;
    } else {
        bn = L % NBN; const int t2 = L / NBN; z = t2 % NZ; bm = t2 / NZ;
    }

    A  += (i64)z * sA;
    Bt += (i64)(z & zmaskBt) * sBt;
    const float* bp = bias;
    int zb = z;
    if (bias2 != nullptr && z >= NZ / 2) { bp = bias2; zb = z - NZ / 2; }
    if (bp) bp += (i64)zb * sBias;
    const int kb = z * koff;

    const int bmp = bm * 128, bnp = bn * 128;
    const int tid = threadIdx.x;
    const int w = tid >> 6, l = tid & 63;
    const int wr = w >> 1, wc = w & 1;
    const int kgrp = l >> 4, lr = l & 15;

    const u16* Ab = A + (i64)bmp * lda;
    const u16* Bb = Bt + (i64)bnp * ldbt;

    f32x4 acc[4][4];
    #pragma unroll
    for (int i = 0; i < 4; ++i)
        #pragma unroll
        for (int j = 0; j < 4; ++j)
            acc[i][j] = (f32x4){0.f, 0.f, 0.f, 0.f};

    for (int k0i = 0; k0i < K; k0i += 64) {
        const int k0 = kb + k0i;
        if (k0i) __syncthreads();
        #pragma unroll
        for (int t = 0; t < 4; ++t) {
            const int idx = t * 256 + tid;
            const int r = idx >> 3, s = idx & 7;
            const int ss = s ^ (r & 7);
            const u16* src;
            if (CATK) {
                src = A + (i64)(k0 / Dv) * BND + (i64)(bmp + r) * Dv + (k0 % Dv) + ss * 8;
            } else {
                src = Ab + (i64)r * lda + k0 + ss * 8;
            }
            gl_lds16(src, &Asb[(t * 256 + w * 64) * 8]);
        }
        #pragma unroll
        for (int t = 0; t < 4; ++t) {
            const int idx = t * 256 + tid;
            const int r = idx >> 3, s = idx & 7;
            const int ss = s ^ (r & 7);
            gl_lds16(Bb + (i64)r * ldbt + k0 + ss * 8, &Bsb[(t * 256 + w * 64) * 8]);
        }
        __syncthreads();

        #pragma unroll
        for (int ks = 0; ks < 2; ++ks) {
            const int slot = ks * 4 + kgrp;
            short8 a[4], b[4];
            #pragma unroll
            for (int i = 0; i < 4; ++i) {
                const int r = wc * 64 + i * 16 + lr;
                a[i] = *(const short8*)&Bsb[r * 64 + ((slot ^ (r & 7)) << 3)];
            }
            #pragma unroll
            for (int j = 0; j < 4; ++j) {
                const int r = wr * 64 + j * 16 + lr;
                b[j] = *(const short8*)&Asb[r * 64 + ((slot ^ (r & 7)) << 3)];
            }
            #pragma unroll
            for (int i = 0; i < 4; ++i)
                #pragma unroll
                for (int j = 0; j < 4; ++j)
                    acc[i][j] = __builtin_amdgcn_mfma_f32_16x16x32_bf16(
                        a[i], b[j], acc[i][j], 0, 0, 0);
        }
    }

    f32x4 bj[4];
    #pragma unroll
    for (int i = 0; i < 4; ++i) {
        const int nb = bnp + wc * 64 + i * 16 + kgrp * 4;
        bj[i] = bp ? *(const f32x4*)&bp[nb] : (f32x4){0.f, 0.f, 0.f, 0.f};
    }

    #pragma unroll
    for (int j = 0; j < 4; ++j) {
        const int m = bmp + wr * 64 + j * 16 + lr;
        #pragma unroll
        for (int i = 0; i < 4; ++i) {
            const int nb = bnp + wc * 64 + i * 16 + kgrp * 4;
            const i64 off = (i64)z * sC + (i64)m * ldc + nb;
            f32x4 v = acc[i][j] + bj[i];
            if (EPI == 0) {
                *(f32x4*)&((float*)Cv)[off] = v;
            } else if (EPI == 1) {
                ushort4 o;
                o.x = f2bf(v[0]); o.y = f2bf(v[1]);
                o.z = f2bf(v[2]); o.w = f2bf(v[3]);
                *(ushort4*)&((u16*)Cv)[off] = o;
            } else {
                u16* xp = (u16*)Cv + off;
                ushort4 old = *(const ushort4*)xp;
                ushort4 o;
                o.x = f2bf(bf2f(old.x) + fmaxf(v[0], 0.f));
                o.y = f2bf(bf2f(old.y) + fmaxf(v[1], 0.f));
                o.z = f2bf(bf2f(old.z) + fmaxf(v[2], 0.f));
                o.w = f2bf(bf2f(old.w) + fmaxf(v[3], 0.f));
                *(ushort4*)xp = o;
            }
        }
    }
}

// ---------------------------------------------------------------------------
// FUSED scores + masked-select + row softmax.
// Block = (b, h, 64-row n-strip); grid 512 (b = bid&7 XCD pin, h fastest).
// Inner engine = r4's proven 2-buf / vmcnt(4) schedule, 9 phases per m-tile
// (3 edges x 3 K-chunks), looped over 16 m-tiles = 144 phases (same total
// staging/MFMA as the 103us kernel). Wave w owns rows n0+w*16..+16; each
// lane owns ONE row (n = n0 + w*16 + lr) -> row reduce = 2 shfl_xor (kgrp).
// Per m-tile epilogue: adj-select -> raw bf16 S to gab + online (m,l).
// Pass 2: re-read own raw tiles (L2 / same-thread coherent), write final
// ga f32 (output) + P bf16 to gab in place. Deletes the softmax dispatch
// and its 134MB ga re-read.
// ---------------------------------------------------------------------------
__global__ __launch_bounds__(256) void scores_sm_fused(
    const u16* __restrict__ qb, const u16* __restrict__ kb,
    const int* __restrict__ adj, u16* __restrict__ gab,
    float* __restrict__ gaf)
{
    __shared__ u16 Qs[2][64 * 64];
    __shared__ u16 Ks[2][64 * 64];

    const int bid = blockIdx.x;
    const int b = bid & 7;
    const int t2 = bid >> 3;          // [0,64)
    const int h = t2 & 3;             // h fastest: adj L2 reuse across h
    const int ns = t2 >> 2;           // [0,16) n-strip
    const int n0 = ns * 64;
    const int zga = h * 8 + b;

    const int tid = threadIdx.x;
    const int w = tid >> 6, l = tid & 63;
    const int kgrp = l >> 4, lr = l & 15;
    const int n = n0 + w * 16 + lr;   // this lane's row

    const i64 qoff   = ((i64)b * Nv + n0) * Dv + h * DKv;
    const i64 kbase0 = ((i64)b * Nv) * Dv + h * DKv;

    const float scale = 0.07216878364870323f;  // 1/sqrt(192)

#define STG(mt_, e_, kc_, bp_) { \
    const u16* qe_ = qb + (i64)(e_) * BND + qoff + (kc_) * 64; \
    const u16* ke_ = kb + (i64)(e_) * BND + kbase0 + (i64)(mt_) * 64 * Dv + (kc_) * 64; \
    u16* Qd_ = Qs[bp_]; u16* Kd_ = Ks[bp_]; \
    _Pragma("unroll") \
    for (int t = 0; t < 2; ++t) { \
        const int idx2 = t * 256 + tid; \
        const int r = idx2 >> 3, s = idx2 & 7; \
        const int ss = s ^ (r & 7); \
        gl_lds16(qe_ + (i64)r * Dv + ss * 8, &Qd_[(t * 256 + w * 64) * 8]); \
        gl_lds16(ke_ + (i64)r * Dv + ss * 8, &Kd_[(t * 256 + w * 64) * 8]); \
    } }

    f32x4 acc[3][4];   // [edge][m-frag (reg dim)]; n-frag count = 1
    #pragma unroll
    for (int e = 0; e < 3; ++e)
        #pragma unroll
        for (int i = 0; i < 4; ++i)
            acc[e][i] = (f32x4){0.f, 0.f, 0.f, 0.f};

    float rm = -3.0e38f, rl = 0.f;   // running row max / exp-sum
    int cur = 0;
    STG(0, 0, 0, 0)

    for (int mt = 0; mt < 16; ++mt) {
        #pragma unroll
        for (int e = 0; e < 3; ++e) {
            #pragma unroll
            for (int kc = 0; kc < 3; ++kc) {
                if (!(mt == 15 && e == 2 && kc == 2)) {
                    int e2 = e, kc2 = kc + 1, mtd = 0;
                    if (kc2 == 3) { kc2 = 0; e2 = e + 1; }
                    if (e2 == 3) { e2 = 0; mtd = 1; }
                    STG(mt + mtd, e2, kc2, cur ^ 1)
                    asm volatile("s_waitcnt vmcnt(4)" ::: "memory");
                } else {
                    asm volatile("s_waitcnt vmcnt(0)" ::: "memory");
                }
                __builtin_amdgcn_s_barrier();
                asm volatile("" ::: "memory");

                const u16* Qc = Qs[cur];
                const u16* Kc = Ks[cur];
                #pragma unroll
                for (int ks = 0; ks < 2; ++ks) {
                    const int slot = ks * 4 + kgrp;
                    short8 qv;
                    {
                        const int r = w * 16 + lr;
                        qv = *(const short8*)&Qc[r * 64 + ((slot ^ (r & 7)) << 3)];
                    }
                    #pragma unroll
                    for (int i = 0; i < 4; ++i) {
                        const int r = i * 16 + lr;
                        short8 a = *(const short8*)&Kc[r * 64 + ((slot ^ (r & 7)) << 3)];
                        acc[e][i] = __builtin_amdgcn_mfma_f32_16x16x32_bf16(
                            a, qv, acc[e][i], 0, 0, 0);
                    }
                }
                asm volatile("s_waitcnt lgkmcnt(0)" ::: "memory");
                __builtin_amdgcn_s_barrier();
                cur ^= 1;
            }
        }

        // ---- m-tile epilogue: mask, online softmax stats, raw store ----
        const int m0 = mt * 64;
        float fin[4][4];
        #pragma unroll
        for (int i = 0; i < 4; ++i) {
            const int mb = m0 + i * 16 + kgrp * 4;
            const int4 av = *(const int4*)&adj[((i64)b * Nv + n) * Nv + mb];
            const int avv[4] = {av.x, av.y, av.z, av.w};
            #pragma unroll
            for (int rg = 0; rg < 4; ++rg) {
                float f = 0.f;
                if (avv[rg] == 1) f = acc[0][i][rg];
                else if (avv[rg] == 2) f = acc[1][i][rg];
                else if (avv[rg] == 3) f = acc[2][i][rg];
                f *= scale;
                if (f == 0.f) f = -1e9f;
                fin[i][rg] = f;
            }
        }

        float tmax = fin[0][0];
        #pragma unroll
        for (int i = 0; i < 4; ++i)
            #pragma unroll
            for (int rg = 0; rg < 4; ++rg)
                tmax = fmaxf(tmax, fin[i][rg]);
        tmax = fmaxf(tmax, __shfl_xor(tmax, 16));
        tmax = fmaxf(tmax, __shfl_xor(tmax, 32));

        float tsum = 0.f;
        #pragma unroll
        for (int i = 0; i < 4; ++i)
            #pragma unroll
            for (int rg = 0; rg < 4; ++rg)
                tsum += expf(fin[i][rg] - tmax);
        tsum += __shfl_xor(tsum, 16);
        tsum += __shfl_xor(tsum, 32);

        const float mnew = fmaxf(rm, tmax);
        rl = rl * expf(rm - mnew) + tsum * expf(tmax - mnew);
        rm = mnew;

        #pragma unroll
        for (int i = 0; i < 4; ++i) {
            ushort4 o;
            o.x = f2bf(fin[i][0]); o.y = f2bf(fin[i][1]);
            o.z = f2bf(fin[i][2]); o.w = f2bf(fin[i][3]);
            *(ushort4*)&gab[((i64)zga * Nv + n) * Nv + m0 + i * 16 + kgrp * 4] = o;
        }

        #pragma unroll
        for (int e = 0; e < 3; ++e)
            #pragma unroll
            for (int i = 0; i < 4; ++i)
                acc[e][i] = (f32x4){0.f, 0.f, 0.f, 0.f};
    }
#undef STG

    // ---- pass 2: finalize softmax, write ga f32 + P bf16 ----
    asm volatile("s_waitcnt vmcnt(0)" ::: "memory");   // raw stores done
    const float inv = 1.0f / rl;
    for (int mt = 0; mt < 16; ++mt) {
        #pragma unroll
        for (int i = 0; i < 4; ++i) {
            const i64 off = ((i64)zga * Nv + n) * Nv + mt * 64 + i * 16 + kgrp * 4;
            const ushort4 raw = *(const ushort4*)&gab[off];
            f32x4 p;
            p[0] = expf(bf2f(raw.x) - rm) * inv;
            p[1] = expf(bf2f(raw.y) - rm) * inv;
            p[2] = expf(bf2f(raw.z) - rm) * inv;
            p[3] = expf(bf2f(raw.w) - rm) * inv;
            *(f32x4*)&gaf[off] = p;
            ushort4 o;
            o.x = f2bf(p[0]); o.y = f2bf(p[1]);
            o.z = f2bf(p[2]); o.w = f2bf(p[3]);
            *(ushort4*)&gab[off] = o;
        }
    }
}

// nodes f32 -> nodesb bf16 + X broadcast x4
__global__ __launch_bounds__(256) void prep_k(const float* __restrict__ nodes,
                                              u16* __restrict__ nodesb,
                                              u16* __restrict__ Xb)
{
    const i64 i = (i64)blockIdx.x * 256 + threadIdx.x;
    float4 v = ((const float4*)nodes)[i];
    ushort4 o;
    o.x = f2bf(v.x); o.y = f2bf(v.y); o.z = f2bf(v.z); o.w = f2bf(v.w);
    ((ushort4*)nodesb)[i] = o;
    const i64 q4 = BND / 4;
    #pragma unroll
    for (int h = 0; h < Hh; ++h) ((ushort4*)Xb)[(i64)h * q4 + i] = o;
}

// all weight transposes in one dispatch
__global__ __launch_bounds__(256) void trans_all(
    const float* __restrict__ Wq, const float* __restrict__ Wk,
    const float* __restrict__ gcnW, const float* __restrict__ Wagg,
    u16* __restrict__ wqkt, u16* __restrict__ gcnWt, u16* __restrict__ waggt)
{
    const int z = blockIdx.z;
    const i64 W768 = (i64)768 * 768;
    const float* src;
    u16* dst;
    int ldo;
    if (z < 3)      { src = Wq + z * W768;        dst = wqkt + z * W768;          ldo = 768; }
    else if (z < 6) { src = Wk + (z - 3) * W768;  dst = wqkt + (i64)z * W768;     ldo = 768; }
    else if (z < 8) { src = gcnW + (z - 6) * W768; dst = gcnWt + (i64)(z - 6) * W768; ldo = 768; }
    else            { src = Wagg + (i64)(z - 8) * W768; dst = waggt + (i64)(z - 8) * 768; ldo = 3072; }

    __shared__ u16 t[32][33];
    const int c0 = blockIdx.x * 32, r0 = blockIdx.y * 32;
    const int tx = threadIdx.x & 31, ty = threadIdx.x >> 5;
    #pragma unroll
    for (int i = ty; i < 32; i += 8)
        t[i][tx] = f2bf(src[(i64)(r0 + i) * 768 + c0 + tx]);
    __syncthreads();
    #pragma unroll
    for (int i = ty; i < 32; i += 8)
        dst[(i64)(c0 + i) * ldo + r0 + tx] = t[tx][i];
}

// out = p0 + p1 + bias (split-K reduce)
__global__ __launch_bounds__(256) void addbias_k(
    const float* __restrict__ p0, const float* __restrict__ p1,
    const float* __restrict__ bias, float* __restrict__ out)
{
    const i64 i4 = (i64)blockIdx.x * 256 + threadIdx.x;
    const int nb = (int)((i4 * 4) % Dv);
    float4 a = ((const float4*)p0)[i4];
    float4 b = ((const float4*)p1)[i4];
    float4 bv = *(const float4*)&bias[nb];
    float4 o;
    o.x = a.x + b.x + bv.x; o.y = a.y + b.y + bv.y;
    o.z = a.z + b.z + bv.z; o.w = a.w + b.w + bv.w;
    ((float4*)out)[i4] = o;
}

// ---------------------------------------------------------------------------
extern "C" void kernel_launch(void* const* d_in, const int* in_sizes, int n_in,
                              void* d_out, int out_size, void* d_ws, size_t ws_size,
                              hipStream_t stream)
{
    const float* nodes = (const float*)d_in[0];
    const int*   adj   = (const int*)d_in[1];
    const float* Wq    = (const float*)d_in[2];
    const float* bq    = (const float*)d_in[3];
    const float* Wk    = (const float*)d_in[4];
    const float* bk    = (const float*)d_in[5];
    const float* gcnW  = (const float*)d_in[6];
    const float* gcnb  = (const float*)d_in[7];
    const float* Wagg  = (const float*)d_in[8];
    const float* bagg  = (const float*)d_in[9];

    float* out = (float*)d_out;             // (B,N,D) f32
    float* gaf = out + BND;                 // (H,B,N,N) f32

    const i64 W768 = (i64)768 * 768;
    const i64 HTZ  = (i64)768 * 1024;       // per-z H^T slab [768][1024]
    u16* ws     = (u16*)d_ws;
    // region 1: ws[0 .. 6BND)  — time-shared:
    u16* qb     = ws;                       //   3*BND (q, phase 1)
    u16* kb2    = ws + 3 * BND;             //   3*BND (k, phase 1)
    u16* Htz    = ws;                       //   32*HTZ (GCN phase; q/k dead)
    float* part = (float*)ws;               //   2*BND f32 (final; Htz dead)
    // fixed:
    u16* nodesb = ws + 6 * BND;             // BND
    u16* gcnWt  = nodesb + BND;             // 2*W768
    u16* waggt  = gcnWt + 2 * W768;         // 4*W768
    u16* Xb     = waggt + 4 * W768;         // HBND
    // region 2: ws2 (HBND u16) — wqkt early, then raw-S/P (gab) persistent:
    u16* ws2    = Xb + HBND;
    u16* wqkt   = ws2;                      //   6*W768 (dead after q/k proj)
    u16* gab    = ws2;                      //   HBND (raw S then P bf16)

    dim3 blk(256);

    prep_k<<<dim3((unsigned)(BND / 4 / 256)), blk, 0, stream>>>(nodes, nodesb, Xb);
    trans_all<<<dim3(24, 24, 12), blk, 0, stream>>>(Wq, Wk, gcnW, Wagg, wqkt, gcnWt, waggt);

    // fused q/k projections: z 0..2 -> q (bias bq), z 3..5 -> k (bias bk)
    gemm_bf16<1, false, 1, 6, 64, 6><<<dim3(2304), blk, 0, stream>>>(
        nodesb, 0, Dv, wqkt, W768, Dv, -1, bq, Dv, bk, qb, BND, Dv, Dv, 0);

    // fused masked scores + softmax: writes ga f32 (output) + P bf16 (gab)
    scores_sm_fused<<<dim3(512), blk, 0, stream>>>(qb, kb2, adj, gab, gaf);

    for (int it = 0; it < 2; ++it) {
        if (it == 0) {
            // iter 0: per-b H0^T = gcnW[0]^T @ nodes[b]^T; Xupd indexes by z&7
            gemm_bf16<1, false, 0, 8, 6, 8><<<dim3(384), blk, 0, stream>>>(
                gcnWt, 0, Dv, nodesb, (i64)Nv * Dv, Dv, 7, nullptr, 0, nullptr,
                Htz, HTZ, 1024, Dv, 0);
            gemm_bf16<2, false, 0, 6, 8, 32><<<dim3(1536), blk, 0, stream>>>(
                gab, (i64)Nv * Nv, Nv, Htz, HTZ, 1024, 7, gcnb, 0, nullptr,
                Xb, (i64)Nv * Dv, Dv, Nv, 0);
        } else {
            // iter 1: per-z H^T = gcnW[1]^T @ X[z]^T
            gemm_bf16<1, false, 0, 8, 6, 32><<<dim3(1536), blk, 0, stream>>>(
                gcnWt + W768, 0, Dv, Xb, (i64)Nv * Dv, Dv, 31, nullptr, 0, nullptr,
                Htz, HTZ, 1024, Dv, 0);
            gemm_bf16<2, false, 0, 6, 8, 32><<<dim3(1536), blk, 0, stream>>>(
                gab, (i64)Nv * Nv, Nv, Htz, HTZ, 1024, 31, gcnb + (i64)Dv, 0, nullptr,
                Xb, (i64)Nv * Dv, Dv, Nv, 0);
        }
    }

    // final: out = cat(X) @ W_agg + b_agg, split-K x2 into f32 partials
    gemm_bf16<0, true, 0, 6, 64, 2><<<dim3(768), blk, 0, stream>>>(
        Xb, 0, Dv, waggt, 0, Hh * Dv, -1, nullptr, 0, nullptr,
        part, BND, Dv, (Hh * Dv) / 2, (Hh * Dv) / 2);

    addbias_k<<<dim3((unsigned)(BND / 4 / 256)), blk, 0, stream>>>(
        part, part + BND, bagg, out);
}

// Round 14
// 597.359 us; speedup vs baseline: 1.0365x; 1.0365x over previous
//
#include <hip/hip_runtime.h>

typedef long long i64;
typedef unsigned short u16;
typedef __attribute__((ext_vector_type(8))) short short8;
typedef __attribute__((ext_vector_type(4))) float f32x4;

#define Bv 8
#define Nv 1024
#define Dv 768
#define Hh 4
#define DKv 192
#define BND ((i64)Bv * Nv * Dv)      /* 6,291,456  */
#define HBND ((i64)Hh * BND)         /* 25,165,824 */

__device__ __forceinline__ u16 f2bf(float f) {
    unsigned u = __builtin_bit_cast(unsigned, f);
    u += 0x7fffu + ((u >> 16) & 1u);
    return (u16)(u >> 16);
}
__device__ __forceinline__ float bf2f(u16 h) {
    unsigned u = ((unsigned)h) << 16;
    return __builtin_bit_cast(float, u);
}

// async global->LDS, 16B per lane. LDS dest must be wave-uniform base.
__device__ __forceinline__ void gl_lds16(const u16* g, u16* l) {
    __builtin_amdgcn_global_load_lds(
        (const __attribute__((address_space(1))) void*)g,
        (__attribute__((address_space(3))) void*)l, 16, 0, 0);
}

#define VMCNT(n) asm volatile("s_waitcnt vmcnt(" #n ")" ::: "memory")

// ---------------------------------------------------------------------------
// bf16 MFMA GEMM (m97-structure): 128x128 tile, BK=64, 256 threads, ~790 TF.
// (unchanged from round 7)
// ---------------------------------------------------------------------------
template <int EPI, bool CATK, int ORD, int NBN, int NBM, int NZ>
__global__ __launch_bounds__(256) void gemm_bf16(
    const u16* __restrict__ A, i64 sA, int lda,
    const u16* __restrict__ Bt, i64 sBt, int ldbt, int zmaskBt,
    const float* __restrict__ bias, i64 sBias, const float* __restrict__ bias2,
    void* __restrict__ Cv, i64 sC, int ldc, int K, int koff)
{
    __shared__ u16 Asb[128 * 64];
    __shared__ u16 Bsb[128 * 64];

    const int L = (blockIdx.x & 7) * ((NBN * NBM * NZ) >> 3) + (blockIdx.x >> 3);
    int bn, bm, z;
    if (ORD == 0) {
        bn = L % NBN; const int t2 = L / NBN; bm = t2 % NBM; z = t2 / NBM;
    } else {
        bn = L % NBN; const int t2 = L / NBN; z = t2 % NZ; bm = t2 / NZ;
    }

    A  += (i64)z * sA;
    Bt += (i64)(z & zmaskBt) * sBt;
    const float* bp = bias;
    int zb = z;
    if (bias2 != nullptr && z >= NZ / 2) { bp = bias2; zb = z - NZ / 2; }
    if (bp) bp += (i64)zb * sBias;
    const int kb = z * koff;

    const int bmp = bm * 128, bnp = bn * 128;
    const int tid = threadIdx.x;
    const int w = tid >> 6, l = tid & 63;
    const int wr = w >> 1, wc = w & 1;
    const int kgrp = l >> 4, lr = l & 15;

    const u16* Ab = A + (i64)bmp * lda;
    const u16* Bb = Bt + (i64)bnp * ldbt;

    f32x4 acc[4][4];
    #pragma unroll
    for (int i = 0; i < 4; ++i)
        #pragma unroll
        for (int j = 0; j < 4; ++j)
            acc[i][j] = (f32x4){0.f, 0.f, 0.f, 0.f};

    for (int k0i = 0; k0i < K; k0i += 64) {
        const int k0 = kb + k0i;
        if (k0i) __syncthreads();
        #pragma unroll
        for (int t = 0; t < 4; ++t) {
            const int idx = t * 256 + tid;
            const int r = idx >> 3, s = idx & 7;
            const int ss = s ^ (r & 7);
            const u16* src;
            if (CATK) {
                src = A + (i64)(k0 / Dv) * BND + (i64)(bmp + r) * Dv + (k0 % Dv) + ss * 8;
            } else {
                src = Ab + (i64)r * lda + k0 + ss * 8;
            }
            gl_lds16(src, &Asb[(t * 256 + w * 64) * 8]);
        }
        #pragma unroll
        for (int t = 0; t < 4; ++t) {
            const int idx = t * 256 + tid;
            const int r = idx >> 3, s = idx & 7;
            const int ss = s ^ (r & 7);
            gl_lds16(Bb + (i64)r * ldbt + k0 + ss * 8, &Bsb[(t * 256 + w * 64) * 8]);
        }
        __syncthreads();

        #pragma unroll
        for (int ks = 0; ks < 2; ++ks) {
            const int slot = ks * 4 + kgrp;
            short8 a[4], b[4];
            #pragma unroll
            for (int i = 0; i < 4; ++i) {
                const int r = wc * 64 + i * 16 + lr;
                a[i] = *(const short8*)&Bsb[r * 64 + ((slot ^ (r & 7)) << 3)];
            }
            #pragma unroll
            for (int j = 0; j < 4; ++j) {
                const int r = wr * 64 + j * 16 + lr;
                b[j] = *(const short8*)&Asb[r * 64 + ((slot ^ (r & 7)) << 3)];
            }
            #pragma unroll
            for (int i = 0; i < 4; ++i)
                #pragma unroll
                for (int j = 0; j < 4; ++j)
                    acc[i][j] = __builtin_amdgcn_mfma_f32_16x16x32_bf16(
                        a[i], b[j], acc[i][j], 0, 0, 0);
        }
    }

    f32x4 bj[4];
    #pragma unroll
    for (int i = 0; i < 4; ++i) {
        const int nb = bnp + wc * 64 + i * 16 + kgrp * 4;
        bj[i] = bp ? *(const f32x4*)&bp[nb] : (f32x4){0.f, 0.f, 0.f, 0.f};
    }

    #pragma unroll
    for (int j = 0; j < 4; ++j) {
        const int m = bmp + wr * 64 + j * 16 + lr;
        #pragma unroll
        for (int i = 0; i < 4; ++i) {
            const int nb = bnp + wc * 64 + i * 16 + kgrp * 4;
            const i64 off = (i64)z * sC + (i64)m * ldc + nb;
            f32x4 v = acc[i][j] + bj[i];
            if (EPI == 0) {
                *(f32x4*)&((float*)Cv)[off] = v;
            } else if (EPI == 1) {
                ushort4 o;
                o.x = f2bf(v[0]); o.y = f2bf(v[1]);
                o.z = f2bf(v[2]); o.w = f2bf(v[3]);
                *(ushort4*)&((u16*)Cv)[off] = o;
            } else {
                u16* xp = (u16*)Cv + off;
                ushort4 old = *(const ushort4*)xp;
                ushort4 o;
                o.x = f2bf(bf2f(old.x) + fmaxf(v[0], 0.f));
                o.y = f2bf(bf2f(old.y) + fmaxf(v[1], 0.f));
                o.z = f2bf(bf2f(old.z) + fmaxf(v[2], 0.f));
                o.w = f2bf(bf2f(old.w) + fmaxf(v[3], 0.f));
                *(ushort4*)xp = o;
            }
        }
    }
}

// ---------------------------------------------------------------------------
// Triple-buffered 128m x 256n tile GEMM, BK=64, 512 thr / 8 waves, counted
// vmcnt(6), ONE raw barrier per K-tile (T3/T4 style, race-proof ledger):
//  - tile t reads buf[t%3]; stages tile t+2 into buf[(t+2)%3] == buf[(t-1)%3],
//    whose readers all passed the end-of-(t-1) barrier (each wave's ds_reads
//    are consumed by its own MFMA before it reaches that barrier).
//  - end-of-tile vmcnt(6): leaves exactly tile-(t+2)'s 6 loads in flight ->
//    tile t+1 fully landed before any wave reads it. Tail: 6 -> 0.
//  - no mid-loop drain to vmcnt(0); compiler manages lgkmcnt for ds_reads.
// Wave (wr=w>>2, wc=w&3): 64m x 64n out; acc[4 m-frag][4 n-frag].
// EPI 1: bf16 store (+optional bias). EPI 2: X += relu(acc+bias) RMW.
// Grid NBN*NBM*NZ (div by 8), XCD-chunked, bn fastest / z slowest.
// ---------------------------------------------------------------------------
template <int EPI, int NBN, int NBM, int NZ>
__global__ __launch_bounds__(512, 2) void gemm_tri(
    const u16* __restrict__ A, i64 sA, int lda,
    const u16* __restrict__ Bt, i64 sBt, int ldbt, int zmask,
    const float* __restrict__ bias,
    u16* __restrict__ Out, i64 sO, int ldo, int K)
{
    __shared__ u16 AsbF[3 * 128 * 64];   // 48 KB
    __shared__ u16 BsbF[3 * 256 * 64];   // 96 KB

    const int L = (blockIdx.x & 7) * ((NBN * NBM * NZ) >> 3) + (blockIdx.x >> 3);
    const int bn = L % NBN;
    const int t2 = L / NBN;
    const int bm = t2 % NBM;
    const int z  = t2 / NBM;

    const u16* Ag = A + (i64)z * sA + (i64)(bm * 128) * lda;
    const u16* Bg = Bt + (i64)(z & zmask) * sBt + (i64)(bn * 256) * ldbt;

    const int tid = threadIdx.x;
    const int w = tid >> 6, l = tid & 63;
    const int wr = w >> 2;            // m half (64 rows each)
    const int wc = w & 3;             // n quarter (64 cols each)
    const int kgrp = l >> 4, lr = l & 15;

    f32x4 acc[4][4];
    #pragma unroll
    for (int f = 0; f < 4; ++f)
        #pragma unroll
        for (int g = 0; g < 4; ++g)
            acc[f][g] = (f32x4){0.f, 0.f, 0.f, 0.f};

// stage tile kt_ into buffer bb_: A 2 loads + B 4 loads per thread
#define STG(kt_, bb_) { \
    _Pragma("unroll") \
    for (int q = 0; q < 2; ++q) { \
        const int idx = q * 512 + tid; \
        const int r = idx >> 3, s = idx & 7; \
        const int ss = s ^ (r & 7); \
        gl_lds16(Ag + (i64)r * lda + (kt_) * 64 + ss * 8, \
                 &AsbF[(bb_) * 8192 + (q * 512 + w * 64) * 8]); \
    } \
    _Pragma("unroll") \
    for (int q = 0; q < 4; ++q) { \
        const int idx = q * 512 + tid; \
        const int r = idx >> 3, s = idx & 7; \
        const int ss = s ^ (r & 7); \
        gl_lds16(Bg + (i64)r * ldbt + (kt_) * 64 + ss * 8, \
                 &BsbF[(bb_) * 16384 + (q * 512 + w * 64) * 8]); \
    } }

    const int NT = K / 64;
    int cur = 0, b2 = 2;

    // prologue: stage tiles 0,1; wait tile 0 landed (12 issued, keep 6)
    STG(0, 0)
    STG(1, 1)
    VMCNT(6);
    __builtin_amdgcn_s_barrier();
    asm volatile("" ::: "memory");

    for (int kt = 0; kt < NT; ++kt) {
        const u16* Ac = &AsbF[cur * 8192];
        const u16* Bc = &BsbF[cur * 16384];

        short8 bfr[4][2];
        #pragma unroll
        for (int g = 0; g < 4; ++g)
            #pragma unroll
            for (int ks = 0; ks < 2; ++ks) {
                const int r = wc * 64 + g * 16 + lr;
                const int slot = ks * 4 + kgrp;
                bfr[g][ks] = *(const short8*)&Bc[r * 64 + ((slot ^ (r & 7)) << 3)];
            }

        if (kt < NT - 2) { STG(kt + 2, b2) }

        #pragma unroll
        for (int p = 0; p < 4; ++p) {
            short8 afr[2];
            #pragma unroll
            for (int ks = 0; ks < 2; ++ks) {
                const int r = wr * 64 + p * 16 + lr;
                const int slot = ks * 4 + kgrp;
                afr[ks] = *(const short8*)&Ac[r * 64 + ((slot ^ (r & 7)) << 3)];
            }
            __builtin_amdgcn_s_setprio(1);
            #pragma unroll
            for (int g = 0; g < 4; ++g)
                #pragma unroll
                for (int ks = 0; ks < 2; ++ks)
                    acc[p][g] = __builtin_amdgcn_mfma_f32_16x16x32_bf16(
                        bfr[g][ks], afr[ks], acc[p][g], 0, 0, 0);
            __builtin_amdgcn_s_setprio(0);
        }

        if (kt < NT - 2) { VMCNT(6); }
        else if (kt == NT - 2) { VMCNT(0); }
        if (kt < NT - 1) {
            __builtin_amdgcn_s_barrier();
            asm volatile("" ::: "memory");
        }
        cur = (cur == 2) ? 0 : cur + 1;
        b2  = (b2 == 2) ? 0 : b2 + 1;
    }
#undef STG

    f32x4 bj[4];
    #pragma unroll
    for (int g = 0; g < 4; ++g) {
        const int n = bn * 256 + wc * 64 + g * 16 + kgrp * 4;
        bj[g] = bias ? *(const f32x4*)&bias[n] : (f32x4){0.f, 0.f, 0.f, 0.f};
    }

    #pragma unroll
    for (int f = 0; f < 4; ++f) {
        const int m = bm * 128 + wr * 64 + f * 16 + lr;
        #pragma unroll
        for (int g = 0; g < 4; ++g) {
            const int n = bn * 256 + wc * 64 + g * 16 + kgrp * 4;
            u16* xp = Out + (i64)z * sO + (i64)m * ldo + n;
            f32x4 v = acc[f][g] + bj[g];
            if (EPI == 1) {
                ushort4 o;
                o.x = f2bf(v[0]); o.y = f2bf(v[1]);
                o.z = f2bf(v[2]); o.w = f2bf(v[3]);
                *(ushort4*)xp = o;
            } else {
                ushort4 old = *(const ushort4*)xp;
                ushort4 o;
                o.x = f2bf(bf2f(old.x) + fmaxf(v[0], 0.f));
                o.y = f2bf(bf2f(old.y) + fmaxf(v[1], 0.f));
                o.z = f2bf(bf2f(old.z) + fmaxf(v[2], 0.f));
                o.w = f2bf(bf2f(old.w) + fmaxf(v[3], 0.f));
                *(ushort4*)xp = o;
            }
        }
    }
}

// ---------------------------------------------------------------------------
// Fused 3-edge masked scores — round-4 proven config (103us): 64x64 tile,
// 2-phase double-buffered, counted vmcnt(4), raw barriers, 32KB LDS.
// ---------------------------------------------------------------------------
__global__ __launch_bounds__(256) void scores_mfma(
    const u16* __restrict__ qb, const u16* __restrict__ kb,
    const int* __restrict__ adj, u16* __restrict__ sb)
{
    __shared__ u16 Qs[2][64 * 64];
    __shared__ u16 Ks[2][64 * 64];

    const int bid = blockIdx.x;
    const int b = bid & 7;
    const int t2 = bid >> 3;
    const int h = t2 & 3;
    const int mt = (t2 >> 2) & 15;
    const int nt = t2 >> 6;
    const int m0 = mt * 64, n0 = nt * 64;
    const int zga = h * 8 + b;

    const int tid = threadIdx.x;
    const int w = tid >> 6, l = tid & 63;
    const int wr = w >> 1, wc = w & 1;
    const int kgrp = l >> 4, lr = l & 15;

    const i64 qoff = ((i64)b * Nv + n0) * Dv + h * DKv;
    const i64 koff = ((i64)b * Nv + m0) * Dv + h * DKv;

#define STAGE_SC(ci_, buf_) { \
    const int e_ = (ci_) / 3, k0_ = ((ci_) % 3) * 64; \
    const u16* qe_ = qb + (i64)e_ * BND + qoff; \
    const u16* ke_ = kb + (i64)e_ * BND + koff; \
    _Pragma("unroll") \
    for (int t = 0; t < 2; ++t) { \
        const int idx2 = t * 256 + tid; \
        const int r = idx2 >> 3, s = idx2 & 7; \
        const int ss = s ^ (r & 7); \
        gl_lds16(qe_ + (i64)r * Dv + k0_ + ss * 8, &Qs[buf_][(t * 256 + w * 64) * 8]); \
        gl_lds16(ke_ + (i64)r * Dv + k0_ + ss * 8, &Ks[buf_][(t * 256 + w * 64) * 8]); \
    } }

    int4 adjv[2][2];
    #pragma unroll
    for (int i = 0; i < 2; ++i) {
        const int mb = m0 + wc * 32 + i * 16 + kgrp * 4;
        #pragma unroll
        for (int j = 0; j < 2; ++j) {
            const int n = n0 + wr * 32 + j * 16 + lr;
            adjv[i][j] = *(const int4*)&adj[((i64)b * Nv + n) * Nv + mb];
        }
    }

    f32x4 acc[3][2][2];
    #pragma unroll
    for (int e = 0; e < 3; ++e)
        #pragma unroll
        for (int i = 0; i < 2; ++i)
            #pragma unroll
            for (int j = 0; j < 2; ++j)
                acc[e][i][j] = (f32x4){0.f, 0.f, 0.f, 0.f};

    STAGE_SC(0, 0)

    #pragma unroll
    for (int ci = 0; ci < 9; ++ci) {
        const int cur = ci & 1;
        if (ci < 8) {
            if (cur) { STAGE_SC(ci + 1, 0) } else { STAGE_SC(ci + 1, 1) }
            VMCNT(4);
        } else {
            VMCNT(0);
        }
        __builtin_amdgcn_s_barrier();
        asm volatile("" ::: "memory");

        const int e = ci / 3;
        #pragma unroll
        for (int ks = 0; ks < 2; ++ks) {
            const int slot = ks * 4 + kgrp;
            short8 a[2], bq2[2];
            #pragma unroll
            for (int i = 0; i < 2; ++i) {
                const int r = wc * 32 + i * 16 + lr;
                a[i] = *(const short8*)&Ks[cur][r * 64 + ((slot ^ (r & 7)) << 3)];
            }
            #pragma unroll
            for (int j = 0; j < 2; ++j) {
                const int r = wr * 32 + j * 16 + lr;
                bq2[j] = *(const short8*)&Qs[cur][r * 64 + ((slot ^ (r & 7)) << 3)];
            }
            #pragma unroll
            for (int i = 0; i < 2; ++i)
                #pragma unroll
                for (int j = 0; j < 2; ++j)
                    acc[e][i][j] = __builtin_amdgcn_mfma_f32_16x16x32_bf16(
                        a[i], bq2[j], acc[e][i][j], 0, 0, 0);
        }

        asm volatile("s_waitcnt lgkmcnt(0)" ::: "memory");
        __builtin_amdgcn_s_barrier();
    }
#undef STAGE_SC

    const float scale = 0.07216878364870323f;  // 1/sqrt(192)
    #pragma unroll
    for (int i = 0; i < 2; ++i) {
        const int mb = m0 + wc * 32 + i * 16 + kgrp * 4;
        #pragma unroll
        for (int j = 0; j < 2; ++j) {
            const int n = n0 + wr * 32 + j * 16 + lr;
            const int av[4] = {adjv[i][j].x, adjv[i][j].y, adjv[i][j].z, adjv[i][j].w};
            ushort4 o;
            #pragma unroll
            for (int rg = 0; rg < 4; ++rg) {
                float f = 0.f;
                if (av[rg] == 1) f = acc[0][i][j][rg];
                else if (av[rg] == 2) f = acc[1][i][j][rg];
                else if (av[rg] == 3) f = acc[2][i][j][rg];
                f *= scale;
                if (f == 0.f) f = -1e9f;
                ((u16*)&o)[rg] = f2bf(f);
            }
            *(ushort4*)&sb[((i64)zga * Nv + n) * Nv + mb] = o;
        }
    }
}

// row softmax over 1024 cols: read S bf16, write ga f32 (output) + P bf16
__global__ __launch_bounds__(256) void softmax_k(const u16* __restrict__ sb,
                                                 float* __restrict__ ga,
                                                 u16* __restrict__ gab)
{
    const i64 row = blockIdx.x;
    const int tid = threadIdx.x;
    const int wid = tid >> 6, lane = tid & 63;

    ushort4 sv = *(const ushort4*)&sb[row * (i64)Nv + tid * 4];
    float4 v;
    v.x = bf2f(sv.x); v.y = bf2f(sv.y); v.z = bf2f(sv.z); v.w = bf2f(sv.w);

    float m = fmaxf(fmaxf(v.x, v.y), fmaxf(v.z, v.w));
    #pragma unroll
    for (int o = 32; o >= 1; o >>= 1) m = fmaxf(m, __shfl_xor(m, o));

    __shared__ float red[4];
    if (lane == 0) red[wid] = m;
    __syncthreads();
    m = fmaxf(fmaxf(red[0], red[1]), fmaxf(red[2], red[3]));

    float e0 = expf(v.x - m), e1 = expf(v.y - m), e2 = expf(v.z - m), e3 = expf(v.w - m);
    float s = e0 + e1 + e2 + e3;
    #pragma unroll
    for (int o = 32; o >= 1; o >>= 1) s += __shfl_xor(s, o);
    __syncthreads();
    if (lane == 0) red[wid] = s;
    __syncthreads();
    s = red[0] + red[1] + red[2] + red[3];

    const float inv = 1.0f / s;
    float4 o;
    o.x = e0 * inv; o.y = e1 * inv; o.z = e2 * inv; o.w = e3 * inv;
    *(float4*)&ga[row * (i64)Nv + tid * 4] = o;

    ushort4 ob;
    ob.x = f2bf(o.x); ob.y = f2bf(o.y); ob.z = f2bf(o.z); ob.w = f2bf(o.w);
    *(ushort4*)&gab[row * (i64)Nv + tid * 4] = ob;
}

// nodes f32 -> nodesb bf16 + X broadcast x4
__global__ __launch_bounds__(256) void prep_k(const float* __restrict__ nodes,
                                              u16* __restrict__ nodesb,
                                              u16* __restrict__ Xb)
{
    const i64 i = (i64)blockIdx.x * 256 + threadIdx.x;
    float4 v = ((const float4*)nodes)[i];
    ushort4 o;
    o.x = f2bf(v.x); o.y = f2bf(v.y); o.z = f2bf(v.z); o.w = f2bf(v.w);
    ((ushort4*)nodesb)[i] = o;
    const i64 q4 = BND / 4;
    #pragma unroll
    for (int h = 0; h < Hh; ++h) ((ushort4*)Xb)[(i64)h * q4 + i] = o;
}

// all weight transposes in one dispatch
__global__ __launch_bounds__(256) void trans_all(
    const float* __restrict__ Wq, const float* __restrict__ Wk,
    const float* __restrict__ gcnW, const float* __restrict__ Wagg,
    u16* __restrict__ wqkt, u16* __restrict__ gcnWt, u16* __restrict__ waggt)
{
    const int z = blockIdx.z;
    const i64 W768 = (i64)768 * 768;
    const float* src;
    u16* dst;
    int ldo;
    if (z < 3)      { src = Wq + z * W768;        dst = wqkt + z * W768;          ldo = 768; }
    else if (z < 6) { src = Wk + (z - 3) * W768;  dst = wqkt + (i64)z * W768;     ldo = 768; }
    else if (z < 8) { src = gcnW + (z - 6) * W768; dst = gcnWt + (i64)(z - 6) * W768; ldo = 768; }
    else            { src = Wagg + (i64)(z - 8) * W768; dst = waggt + (i64)(z - 8) * 768; ldo = 3072; }

    __shared__ u16 t[32][33];
    const int c0 = blockIdx.x * 32, r0 = blockIdx.y * 32;
    const int tx = threadIdx.x & 31, ty = threadIdx.x >> 5;
    #pragma unroll
    for (int i = ty; i < 32; i += 8)
        t[i][tx] = f2bf(src[(i64)(r0 + i) * 768 + c0 + tx]);
    __syncthreads();
    #pragma unroll
    for (int i = ty; i < 32; i += 8)
        dst[(i64)(c0 + i) * ldo + r0 + tx] = t[tx][i];
}

// out = p0 + p1 + bias (split-K reduce)
__global__ __launch_bounds__(256) void addbias_k(
    const float* __restrict__ p0, const float* __restrict__ p1,
    const float* __restrict__ bias, float* __restrict__ out)
{
    const i64 i4 = (i64)blockIdx.x * 256 + threadIdx.x;
    const int nb = (int)((i4 * 4) % Dv);
    float4 a = ((const float4*)p0)[i4];
    float4 b = ((const float4*)p1)[i4];
    float4 bv = *(const float4*)&bias[nb];
    float4 o;
    o.x = a.x + b.x + bv.x; o.y = a.y + b.y + bv.y;
    o.z = a.z + b.z + bv.z; o.w = a.w + b.w + bv.w;
    ((float4*)out)[i4] = o;
}

// ---------------------------------------------------------------------------
extern "C" void kernel_launch(void* const* d_in, const int* in_sizes, int n_in,
                              void* d_out, int out_size, void* d_ws, size_t ws_size,
                              hipStream_t stream)
{
    const float* nodes = (const float*)d_in[0];
    const int*   adj   = (const int*)d_in[1];
    const float* Wq    = (const float*)d_in[2];
    const float* bq    = (const float*)d_in[3];
    const float* Wk    = (const float*)d_in[4];
    const float* bk    = (const float*)d_in[5];
    const float* gcnW  = (const float*)d_in[6];
    const float* gcnb  = (const float*)d_in[7];
    const float* Wagg  = (const float*)d_in[8];
    const float* bagg  = (const float*)d_in[9];

    float* out = (float*)d_out;             // (B,N,D) f32
    float* gaf = out + BND;                 // (H,B,N,N) f32

    const i64 W768 = (i64)768 * 768;
    const i64 HTZ  = (i64)768 * 1024;       // per-z H^T slab [768][1024]
    u16* ws     = (u16*)d_ws;
    u16* qb     = ws;                       // 3*BND           (phase 1)
    u16* kb2    = ws + 3 * BND;             // 3*BND           (phase 1)
    u16* gab    = ws;                       // HBND bf16       (alias after scores)
    u16* nodesb = ws + 6 * BND;             // BND
    u16* gcnWt  = nodesb + BND;             // 2*W768
    u16* waggt  = gcnWt + 2 * W768;         // 4*W768
    u16* Xb     = waggt + 4 * W768;         // HBND
    u16* Htz    = Xb + HBND;                // 32*HTZ, time-shared:
    u16* wqkt   = Htz;                      //   6*W768 (dead after q/k proj)
    u16* sbuf   = Htz;                      //   HBND (S bf16; dead after softmax)
    float* part = (float*)Htz;              //   2*BND f32 (final split-K)

    dim3 blk(256);

    prep_k<<<dim3((unsigned)(BND / 4 / 256)), blk, 0, stream>>>(nodes, nodesb, Xb);
    trans_all<<<dim3(24, 24, 12), blk, 0, stream>>>(Wq, Wk, gcnW, Wagg, wqkt, gcnWt, waggt);

    // fused q/k projections: z 0..2 -> q (bias bq), z 3..5 -> k (bias bk)
    gemm_bf16<1, false, 1, 6, 64, 6><<<dim3(2304), blk, 0, stream>>>(
        nodesb, 0, Dv, wqkt, W768, Dv, -1, bq, Dv, bk, qb, BND, Dv, Dv, 0);

    // fused masked scores -> S bf16 scratch (r4 proven config)
    scores_mfma<<<dim3(8192), blk, 0, stream>>>(qb, kb2, adj, sbuf);

    // softmax: ga f32 (output) + P bf16
    softmax_k<<<dim3(Hh * Bv * Nv), blk, 0, stream>>>(sbuf, gaf, gab);

    for (int it = 0; it < 2; ++it) {
        if (it == 0) {
            // iter 0: per-b H0^T = gcnW[0]^T @ nodes[b]^T (128^2 path, small)
            gemm_bf16<1, false, 0, 8, 6, 8><<<dim3(384), blk, 0, stream>>>(
                gcnWt, 0, Dv, nodesb, (i64)Nv * Dv, Dv, 7, nullptr, 0, nullptr,
                Htz, HTZ, 1024, Dv, 0);
            // Xupd0: X += relu(gab[z] @ Htz[z&7]^T + b0)   (tri-buffered)
            gemm_tri<2, 3, 8, 32><<<dim3(768), dim3(512), 0, stream>>>(
                gab, (i64)Nv * Nv, Nv, Htz, HTZ, 1024, 7, gcnb,
                Xb, (i64)Nv * Dv, Dv, Nv);
        } else {
            // Ht1: per-z H^T = gcnW[1]^T @ X[z]^T   (tri-buffered)
            gemm_tri<1, 4, 6, 32><<<dim3(768), dim3(512), 0, stream>>>(
                gcnWt + W768, 0, Dv, Xb, (i64)Nv * Dv, Dv, 31, nullptr,
                Htz, HTZ, 1024, Dv);
            // Xupd1
            gemm_tri<2, 3, 8, 32><<<dim3(768), dim3(512), 0, stream>>>(
                gab, (i64)Nv * Nv, Nv, Htz, HTZ, 1024, 31, gcnb + (i64)Dv,
                Xb, (i64)Nv * Dv, Dv, Nv);
        }
    }

    // final: out = cat(X) @ W_agg + b_agg, split-K x2 into f32 partials
    gemm_bf16<0, true, 0, 6, 64, 2><<<dim3(768), blk, 0, stream>>>(
        Xb, 0, Dv, waggt, 0, Hh * Dv, -1, nullptr, 0, nullptr,
        part, BND, Dv, (Hh * Dv) / 2, (Hh * Dv) / 2);

    addbias_k<<<dim3((unsigned)(BND / 4 / 256)), blk, 0, stream>>>(
        part, part + BND, bagg, out);
}

// Round 15
// 543.109 us; speedup vs baseline: 1.1400x; 1.0999x over previous
//
#include <hip/hip_runtime.h>

typedef long long i64;
typedef unsigned short u16;
typedef __attribute__((ext_vector_type(8))) short short8;
typedef __attribute__((ext_vector_type(4))) float f32x4;

#define Bv 8
#define Nv 1024
#define Dv 768
#define Hh 4
#define DKv 192
#define BND ((i64)Bv * Nv * Dv)      /* 6,291,456  */
#define HBND ((i64)Hh * BND)         /* 25,165,824 */

__device__ __forceinline__ u16 f2bf(float f) {
    unsigned u = __builtin_bit_cast(unsigned, f);
    u += 0x7fffu + ((u >> 16) & 1u);
    return (u16)(u >> 16);
}
__device__ __forceinline__ float bf2f(u16 h) {
    unsigned u = ((unsigned)h) << 16;
    return __builtin_bit_cast(float, u);
}

// async global->LDS, 16B per lane. LDS dest must be wave-uniform base.
__device__ __forceinline__ void gl_lds16(const u16* g, u16* l) {
    __builtin_amdgcn_global_load_lds(
        (const __attribute__((address_space(1))) void*)g,
        (__attribute__((address_space(3))) void*)l, 16, 0, 0);
}

// ---------------------------------------------------------------------------
// bf16 MFMA GEMM (m97-structure): 128x128 tile, BK=64, 256 threads (4 waves,
// 64x64 sub-tile each), ~730-790 TF measured. Swapped mfma operand order
// (first operand = Bt rows) -> C/D reg dim runs along contiguous n -> vector
// epilogue. XOR slot swizzle both sides. XCD-chunked 1D swizzle.
// EPI: 0 = f32 store (+bias), 1 = bf16 store (+bias),
//      2 = X-update: X = bf16( bf2f(X) + relu(acc + bias) )  (u16*, RMW)
// CATK: A is X in (h,BN,768) layout; logical k = h*768 + d (cat view).
// bias2: if non-null, z >= NZ/2 uses bias2[z - NZ/2] (fused q/k dispatch).
// zmaskBt: Bt batch offset uses (z & zmaskBt) (shared-Bt indexing).
// ---------------------------------------------------------------------------
template <int EPI, bool CATK, int ORD, int NBN, int NBM, int NZ>
__global__ __launch_bounds__(256) void gemm_bf16(
    const u16* __restrict__ A, i64 sA, int lda,
    const u16* __restrict__ Bt, i64 sBt, int ldbt, int zmaskBt,
    const float* __restrict__ bias, i64 sBias, const float* __restrict__ bias2,
    void* __restrict__ Cv, i64 sC, int ldc, int K, int koff)
{
    __shared__ u16 Asb[128 * 64];
    __shared__ u16 Bsb[128 * 64];

    const int L = (blockIdx.x & 7) * ((NBN * NBM * NZ) >> 3) + (blockIdx.x >> 3);
    int bn, bm, z;
    if (ORD == 0) {
        bn = L % NBN; const int t2 = L / NBN; bm = t2 % NBM; z = t2 / NBM;
    } else {
        bn = L % NBN; const int t2 = L / NBN; z = t2 % NZ; bm = t2 / NZ;
    }

    A  += (i64)z * sA;
    Bt += (i64)(z & zmaskBt) * sBt;
    const float* bp = bias;
    int zb = z;
    if (bias2 != nullptr && z >= NZ / 2) { bp = bias2; zb = z - NZ / 2; }
    if (bp) bp += (i64)zb * sBias;
    const int kb = z * koff;

    const int bmp = bm * 128, bnp = bn * 128;
    const int tid = threadIdx.x;
    const int w = tid >> 6, l = tid & 63;
    const int wr = w >> 1, wc = w & 1;
    const int kgrp = l >> 4, lr = l & 15;

    const u16* Ab = A + (i64)bmp * lda;
    const u16* Bb = Bt + (i64)bnp * ldbt;

    f32x4 acc[4][4];   // [i: n-frag (reg dim)][j: m-frag (lane dim)]
    #pragma unroll
    for (int i = 0; i < 4; ++i)
        #pragma unroll
        for (int j = 0; j < 4; ++j)
            acc[i][j] = (f32x4){0.f, 0.f, 0.f, 0.f};

    for (int k0i = 0; k0i < K; k0i += 64) {
        const int k0 = kb + k0i;
        if (k0i) __syncthreads();
        #pragma unroll
        for (int t = 0; t < 4; ++t) {
            const int idx = t * 256 + tid;
            const int r = idx >> 3, s = idx & 7;
            const int ss = s ^ (r & 7);
            const u16* src;
            if (CATK) {
                src = A + (i64)(k0 / Dv) * BND + (i64)(bmp + r) * Dv + (k0 % Dv) + ss * 8;
            } else {
                src = Ab + (i64)r * lda + k0 + ss * 8;
            }
            gl_lds16(src, &Asb[(t * 256 + w * 64) * 8]);
        }
        #pragma unroll
        for (int t = 0; t < 4; ++t) {
            const int idx = t * 256 + tid;
            const int r = idx >> 3, s = idx & 7;
            const int ss = s ^ (r & 7);
            gl_lds16(Bb + (i64)r * ldbt + k0 + ss * 8, &Bsb[(t * 256 + w * 64) * 8]);
        }
        __syncthreads();

        #pragma unroll
        for (int ks = 0; ks < 2; ++ks) {
            const int slot = ks * 4 + kgrp;
            short8 a[4], b[4];
            #pragma unroll
            for (int i = 0; i < 4; ++i) {          // Bt rows (n side)
                const int r = wc * 64 + i * 16 + lr;
                a[i] = *(const short8*)&Bsb[r * 64 + ((slot ^ (r & 7)) << 3)];
            }
            #pragma unroll
            for (int j = 0; j < 4; ++j) {          // A rows (m side)
                const int r = wr * 64 + j * 16 + lr;
                b[j] = *(const short8*)&Asb[r * 64 + ((slot ^ (r & 7)) << 3)];
            }
            #pragma unroll
            for (int i = 0; i < 4; ++i)
                #pragma unroll
                for (int j = 0; j < 4; ++j)
                    acc[i][j] = __builtin_amdgcn_mfma_f32_16x16x32_bf16(
                        a[i], b[j], acc[i][j], 0, 0, 0);
        }
    }

    f32x4 bj[4];
    #pragma unroll
    for (int i = 0; i < 4; ++i) {
        const int nb = bnp + wc * 64 + i * 16 + kgrp * 4;
        bj[i] = bp ? *(const f32x4*)&bp[nb] : (f32x4){0.f, 0.f, 0.f, 0.f};
    }

    #pragma unroll
    for (int j = 0; j < 4; ++j) {
        const int m = bmp + wr * 64 + j * 16 + lr;
        #pragma unroll
        for (int i = 0; i < 4; ++i) {
            const int nb = bnp + wc * 64 + i * 16 + kgrp * 4;
            const i64 off = (i64)z * sC + (i64)m * ldc + nb;
            f32x4 v = acc[i][j] + bj[i];
            if (EPI == 0) {
                *(f32x4*)&((float*)Cv)[off] = v;
            } else if (EPI == 1) {
                ushort4 o;
                o.x = f2bf(v[0]); o.y = f2bf(v[1]);
                o.z = f2bf(v[2]); o.w = f2bf(v[3]);
                *(ushort4*)&((u16*)Cv)[off] = o;
            } else {
                u16* xp = (u16*)Cv + off;
                ushort4 old = *(const ushort4*)xp;
                ushort4 o;
                o.x = f2bf(bf2f(old.x) + fmaxf(v[0], 0.f));
                o.y = f2bf(bf2f(old.y) + fmaxf(v[1], 0.f));
                o.z = f2bf(bf2f(old.z) + fmaxf(v[2], 0.f));
                o.w = f2bf(bf2f(old.w) + fmaxf(v[3], 0.f));
                *(ushort4*)xp = o;
            }
        }
    }
}

// ---------------------------------------------------------------------------
// Fused 3-edge masked scores — round-4 proven config (103us, best of 8
// variants): 64x64 tile, 2-phase double-buffered, counted vmcnt(4), raw
// barriers, 32KB LDS, grid 8192 (b per XCD, h fastest, mt, nt).
// ---------------------------------------------------------------------------
__global__ __launch_bounds__(256) void scores_mfma(
    const u16* __restrict__ qb, const u16* __restrict__ kb,
    const int* __restrict__ adj, u16* __restrict__ sb)
{
    __shared__ u16 Qs[2][64 * 64];
    __shared__ u16 Ks[2][64 * 64];

    const int bid = blockIdx.x;
    const int b = bid & 7;
    const int t2 = bid >> 3;
    const int h = t2 & 3;
    const int mt = (t2 >> 2) & 15;
    const int nt = t2 >> 6;
    const int m0 = mt * 64, n0 = nt * 64;
    const int zga = h * 8 + b;

    const int tid = threadIdx.x;
    const int w = tid >> 6, l = tid & 63;
    const int wr = w >> 1, wc = w & 1;
    const int kgrp = l >> 4, lr = l & 15;

    const i64 qoff = ((i64)b * Nv + n0) * Dv + h * DKv;
    const i64 koff = ((i64)b * Nv + m0) * Dv + h * DKv;

#define STAGE_SC(ci_, buf_) { \
    const int e_ = (ci_) / 3, k0_ = ((ci_) % 3) * 64; \
    const u16* qe_ = qb + (i64)e_ * BND + qoff; \
    const u16* ke_ = kb + (i64)e_ * BND + koff; \
    _Pragma("unroll") \
    for (int t = 0; t < 2; ++t) { \
        const int idx2 = t * 256 + tid; \
        const int r = idx2 >> 3, s = idx2 & 7; \
        const int ss = s ^ (r & 7); \
        gl_lds16(qe_ + (i64)r * Dv + k0_ + ss * 8, &Qs[buf_][(t * 256 + w * 64) * 8]); \
        gl_lds16(ke_ + (i64)r * Dv + k0_ + ss * 8, &Ks[buf_][(t * 256 + w * 64) * 8]); \
    } }

    int4 adjv[2][2];
    #pragma unroll
    for (int i = 0; i < 2; ++i) {
        const int mb = m0 + wc * 32 + i * 16 + kgrp * 4;
        #pragma unroll
        for (int j = 0; j < 2; ++j) {
            const int n = n0 + wr * 32 + j * 16 + lr;
            adjv[i][j] = *(const int4*)&adj[((i64)b * Nv + n) * Nv + mb];
        }
    }

    f32x4 acc[3][2][2];
    #pragma unroll
    for (int e = 0; e < 3; ++e)
        #pragma unroll
        for (int i = 0; i < 2; ++i)
            #pragma unroll
            for (int j = 0; j < 2; ++j)
                acc[e][i][j] = (f32x4){0.f, 0.f, 0.f, 0.f};

    STAGE_SC(0, 0)

    #pragma unroll
    for (int ci = 0; ci < 9; ++ci) {
        const int cur = ci & 1;
        if (ci < 8) {
            if (cur) { STAGE_SC(ci + 1, 0) } else { STAGE_SC(ci + 1, 1) }
            asm volatile("s_waitcnt vmcnt(4)" ::: "memory");
        } else {
            asm volatile("s_waitcnt vmcnt(0)" ::: "memory");
        }
        __builtin_amdgcn_s_barrier();
        asm volatile("" ::: "memory");

        const int e = ci / 3;
        #pragma unroll
        for (int ks = 0; ks < 2; ++ks) {
            const int slot = ks * 4 + kgrp;
            short8 a[2], bq2[2];
            #pragma unroll
            for (int i = 0; i < 2; ++i) {          // K rows (m side, reg dim)
                const int r = wc * 32 + i * 16 + lr;
                a[i] = *(const short8*)&Ks[cur][r * 64 + ((slot ^ (r & 7)) << 3)];
            }
            #pragma unroll
            for (int j = 0; j < 2; ++j) {          // Q rows (n side, lane dim)
                const int r = wr * 32 + j * 16 + lr;
                bq2[j] = *(const short8*)&Qs[cur][r * 64 + ((slot ^ (r & 7)) << 3)];
            }
            #pragma unroll
            for (int i = 0; i < 2; ++i)
                #pragma unroll
                for (int j = 0; j < 2; ++j)
                    acc[e][i][j] = __builtin_amdgcn_mfma_f32_16x16x32_bf16(
                        a[i], bq2[j], acc[e][i][j], 0, 0, 0);
        }

        asm volatile("s_waitcnt lgkmcnt(0)" ::: "memory");
        __builtin_amdgcn_s_barrier();
    }
#undef STAGE_SC

    const float scale = 0.07216878364870323f;  // 1/sqrt(192)
    #pragma unroll
    for (int i = 0; i < 2; ++i) {
        const int mb = m0 + wc * 32 + i * 16 + kgrp * 4;
        #pragma unroll
        for (int j = 0; j < 2; ++j) {
            const int n = n0 + wr * 32 + j * 16 + lr;
            const int av[4] = {adjv[i][j].x, adjv[i][j].y, adjv[i][j].z, adjv[i][j].w};
            ushort4 o;
            #pragma unroll
            for (int rg = 0; rg < 4; ++rg) {
                float f = 0.f;
                if (av[rg] == 1) f = acc[0][i][j][rg];
                else if (av[rg] == 2) f = acc[1][i][j][rg];
                else if (av[rg] == 3) f = acc[2][i][j][rg];
                f *= scale;
                if (f == 0.f) f = -1e9f;
                ((u16*)&o)[rg] = f2bf(f);
            }
            *(ushort4*)&sb[((i64)zga * Nv + n) * Nv + mb] = o;
        }
    }
}

// row softmax over 1024 cols: read S bf16, write ga f32 (output) + P bf16
__global__ __launch_bounds__(256) void softmax_k(const u16* __restrict__ sb,
                                                 float* __restrict__ ga,
                                                 u16* __restrict__ gab)
{
    const i64 row = blockIdx.x;
    const int tid = threadIdx.x;
    const int wid = tid >> 6, lane = tid & 63;

    ushort4 sv = *(const ushort4*)&sb[row * (i64)Nv + tid * 4];
    float4 v;
    v.x = bf2f(sv.x); v.y = bf2f(sv.y); v.z = bf2f(sv.z); v.w = bf2f(sv.w);

    float m = fmaxf(fmaxf(v.x, v.y), fmaxf(v.z, v.w));
    #pragma unroll
    for (int o = 32; o >= 1; o >>= 1) m = fmaxf(m, __shfl_xor(m, o));

    __shared__ float red[4];
    if (lane == 0) red[wid] = m;
    __syncthreads();
    m = fmaxf(fmaxf(red[0], red[1]), fmaxf(red[2], red[3]));

    float e0 = expf(v.x - m), e1 = expf(v.y - m), e2 = expf(v.z - m), e3 = expf(v.w - m);
    float s = e0 + e1 + e2 + e3;
    #pragma unroll
    for (int o = 32; o >= 1; o >>= 1) s += __shfl_xor(s, o);
    __syncthreads();
    if (lane == 0) red[wid] = s;
    __syncthreads();
    s = red[0] + red[1] + red[2] + red[3];

    const float inv = 1.0f / s;
    float4 o;
    o.x = e0 * inv; o.y = e1 * inv; o.z = e2 * inv; o.w = e3 * inv;
    *(float4*)&ga[row * (i64)Nv + tid * 4] = o;

    ushort4 ob;
    ob.x = f2bf(o.x); ob.y = f2bf(o.y); ob.z = f2bf(o.z); ob.w = f2bf(o.w);
    *(ushort4*)&gab[row * (i64)Nv + tid * 4] = ob;
}

// nodes f32 -> nodesb bf16 + X broadcast x4 (one read, five writes)
__global__ __launch_bounds__(256) void prep_k(const float* __restrict__ nodes,
                                              u16* __restrict__ nodesb,
                                              u16* __restrict__ Xb)
{
    const i64 i = (i64)blockIdx.x * 256 + threadIdx.x;  // over BND/4
    float4 v = ((const float4*)nodes)[i];
    ushort4 o;
    o.x = f2bf(v.x); o.y = f2bf(v.y); o.z = f2bf(v.z); o.w = f2bf(v.w);
    ((ushort4*)nodesb)[i] = o;
    const i64 q4 = BND / 4;
    #pragma unroll
    for (int h = 0; h < Hh; ++h) ((ushort4*)Xb)[(i64)h * q4 + i] = o;
}

// all weight transposes in one dispatch. z<3: Wq[e]; 3..5: Wk[e]; 6,7: gcnW;
// 8..11: Wagg 768-row slice. All 768x768 transposes.
__global__ __launch_bounds__(256) void trans_all(
    const float* __restrict__ Wq, const float* __restrict__ Wk,
    const float* __restrict__ gcnW, const float* __restrict__ Wagg,
    u16* __restrict__ wqkt, u16* __restrict__ gcnWt, u16* __restrict__ waggt)
{
    const int z = blockIdx.z;
    const i64 W768 = (i64)768 * 768;
    const float* src;
    u16* dst;
    int ldo;
    if (z < 3)      { src = Wq + z * W768;        dst = wqkt + z * W768;          ldo = 768; }
    else if (z < 6) { src = Wk + (z - 3) * W768;  dst = wqkt + (i64)z * W768;     ldo = 768; }
    else if (z < 8) { src = gcnW + (z - 6) * W768; dst = gcnWt + (i64)(z - 6) * W768; ldo = 768; }
    else            { src = Wagg + (i64)(z - 8) * W768; dst = waggt + (i64)(z - 8) * 768; ldo = 3072; }

    __shared__ u16 t[32][33];
    const int c0 = blockIdx.x * 32, r0 = blockIdx.y * 32;
    const int tx = threadIdx.x & 31, ty = threadIdx.x >> 5;
    #pragma unroll
    for (int i = ty; i < 32; i += 8)
        t[i][tx] = f2bf(src[(i64)(r0 + i) * 768 + c0 + tx]);
    __syncthreads();
    #pragma unroll
    for (int i = ty; i < 32; i += 8)
        dst[(i64)(c0 + i) * ldo + r0 + tx] = t[tx][i];
}

// out = p0 + p1 + bias (split-K reduce), float4 per thread
__global__ __launch_bounds__(256) void addbias_k(
    const float* __restrict__ p0, const float* __restrict__ p1,
    const float* __restrict__ bias, float* __restrict__ out)
{
    const i64 i4 = (i64)blockIdx.x * 256 + threadIdx.x;  // over BND/4
    const int nb = (int)((i4 * 4) % Dv);
    float4 a = ((const float4*)p0)[i4];
    float4 b = ((const float4*)p1)[i4];
    float4 bv = *(const float4*)&bias[nb];
    float4 o;
    o.x = a.x + b.x + bv.x; o.y = a.y + b.y + bv.y;
    o.z = a.z + b.z + bv.z; o.w = a.w + b.w + bv.w;
    ((float4*)out)[i4] = o;
}

// ---------------------------------------------------------------------------
extern "C" void kernel_launch(void* const* d_in, const int* in_sizes, int n_in,
                              void* d_out, int out_size, void* d_ws, size_t ws_size,
                              hipStream_t stream)
{
    const float* nodes = (const float*)d_in[0];
    const int*   adj   = (const int*)d_in[1];
    const float* Wq    = (const float*)d_in[2];
    const float* bq    = (const float*)d_in[3];
    const float* Wk    = (const float*)d_in[4];
    const float* bk    = (const float*)d_in[5];
    const float* gcnW  = (const float*)d_in[6];
    const float* gcnb  = (const float*)d_in[7];
    const float* Wagg  = (const float*)d_in[8];
    const float* bagg  = (const float*)d_in[9];

    float* out = (float*)d_out;             // (B,N,D) f32
    float* gaf = out + BND;                 // (H,B,N,N) f32

    const i64 W768 = (i64)768 * 768;
    const i64 HTZ  = (i64)768 * 1024;       // per-z H^T slab [768][1024]
    u16* ws     = (u16*)d_ws;
    u16* qb     = ws;                       // 3*BND           (phase 1)
    u16* kb2    = ws + 3 * BND;             // 3*BND           (phase 1)
    u16* gab    = ws;                       // HBND bf16       (alias after scores)
    u16* nodesb = ws + 6 * BND;             // BND
    u16* gcnWt  = nodesb + BND;             // 2*W768
    u16* waggt  = gcnWt + 2 * W768;         // 4*W768
    u16* Xb     = waggt + 4 * W768;         // HBND
    u16* Htz    = Xb + HBND;                // 32*HTZ, time-shared:
    u16* wqkt   = Htz;                      //   6*W768 (dead after q/k proj)
    u16* sbuf   = Htz;                      //   HBND (S bf16; dead after softmax)
    float* part = (float*)Htz;              //   2*BND f32 (final split-K)

    dim3 blk(256);

    prep_k<<<dim3((unsigned)(BND / 4 / 256)), blk, 0, stream>>>(nodes, nodesb, Xb);
    trans_all<<<dim3(24, 24, 12), blk, 0, stream>>>(Wq, Wk, gcnW, Wagg, wqkt, gcnWt, waggt);

    // fused q/k projections: z 0..2 -> q (bias bq), z 3..5 -> k (bias bk)
    gemm_bf16<1, false, 1, 6, 64, 6><<<dim3(2304), blk, 0, stream>>>(
        nodesb, 0, Dv, wqkt, W768, Dv, -1, bq, Dv, bk, qb, BND, Dv, Dv, 0);

    // fused masked scores -> S bf16 scratch (r4 proven config)
    scores_mfma<<<dim3(8192), blk, 0, stream>>>(qb, kb2, adj, sbuf);

    // softmax: ga f32 (output) + P bf16
    softmax_k<<<dim3(Hh * Bv * Nv), blk, 0, stream>>>(sbuf, gaf, gab);

    for (int it = 0; it < 2; ++it) {
        if (it == 0) {
            // iter 0: per-b H0^T = gcnW[0]^T @ nodes[b]^T; Xupd indexes by z&7
            gemm_bf16<1, false, 0, 8, 6, 8><<<dim3(384), blk, 0, stream>>>(
                gcnWt, 0, Dv, nodesb, (i64)Nv * Dv, Dv, 7, nullptr, 0, nullptr,
                Htz, HTZ, 1024, Dv, 0);
            gemm_bf16<2, false, 0, 6, 8, 32><<<dim3(1536), blk, 0, stream>>>(
                gab, (i64)Nv * Nv, Nv, Htz, HTZ, 1024, 7, gcnb, 0, nullptr,
                Xb, (i64)Nv * Dv, Dv, Nv, 0);
        } else {
            // iter 1: per-z H^T = gcnW[1]^T @ X[z]^T
            gemm_bf16<1, false, 0, 8, 6, 32><<<dim3(1536), blk, 0, stream>>>(
                gcnWt + W768, 0, Dv, Xb, (i64)Nv * Dv, Dv, 31, nullptr, 0, nullptr,
                Htz, HTZ, 1024, Dv, 0);
            gemm_bf16<2, false, 0, 6, 8, 32><<<dim3(1536), blk, 0, stream>>>(
                gab, (i64)Nv * Nv, Nv, Htz, HTZ, 1024, 31, gcnb + (i64)Dv, 0, nullptr,
                Xb, (i64)Nv * Dv, Dv, Nv, 0);
        }
    }

    // final: out = cat(X) @ W_agg + b_agg, split-K x2 into f32 partials
    gemm_bf16<0, true, 0, 6, 64, 2><<<dim3(768), blk, 0, stream>>>(
        Xb, 0, Dv, waggt, 0, Hh * Dv, -1, nullptr, 0, nullptr,
        part, BND, Dv, (Hh * Dv) / 2, (Hh * Dv) / 2);

    addbias_k<<<dim3((unsigned)(BND / 4 / 256)), blk, 0, stream>>>(
        part, part + BND, bagg, out);
}